// Round 2
// baseline (127.140 us; speedup 1.0000x reference)
//
#include <hip/hip_runtime.h>

// dqn MLP: 8 -> 5 -> 5 -> 5 -> 5 -> 5 -> 4, fp32.
// layer0: linear only; layers 1-4: linear+relu; layer5: linear+relu.
// BATCH = 2,097,152 rows. Memory-bound streaming kernel.
//
// v2b: lane-contiguous float4 input loads staged through an XOR-swizzled
// LDS tile (conflict-free b128 write AND read), replacing the previous
// stride-2-float4 pattern (2x request amplification, half-used 64B lines
// per instruction). Output stored non-temporally (never re-read).
// Uses clang ext_vector_type for the NT store (HIP float4 class is
// rejected by __builtin_nontemporal_store).

#define IN_DIM 8
#define HID 5
#define OUT_DIM 4
#define BLOCK 256

typedef float f32x4 __attribute__((ext_vector_type(4)));

// Involution on [0,512): XOR bit3 into bit0. For both the write pattern
// (s = t, s = 256+t) and the read pattern (s = 2t, 2t+1), any 8
// consecutive lanes map to 8 distinct float4 bank-quads -> conflict-free
// ds_write_b128 / ds_read_b128.
__device__ __forceinline__ int swz(int s) { return s ^ ((s >> 3) & 1); }

__global__ __launch_bounds__(BLOCK) void dqn_mlp_kernel(
    const float* __restrict__ x,
    const float* __restrict__ W0, const float* __restrict__ b0,
    const float* __restrict__ W1, const float* __restrict__ b1,
    const float* __restrict__ W2, const float* __restrict__ b2,
    const float* __restrict__ W3, const float* __restrict__ b3,
    const float* __restrict__ W4, const float* __restrict__ b4,
    const float* __restrict__ W5, const float* __restrict__ b5,
    float* __restrict__ out, int batch)
{
    __shared__ f32x4 tile[2 * BLOCK];  // 8 KB

    const int t = threadIdx.x;
    const long long rowBase = (long long)blockIdx.x * BLOCK;
    const long long i = rowBase + t;

    const f32x4* __restrict__ xv = reinterpret_cast<const f32x4*>(x);

    float xin[IN_DIM];

    if (rowBase + BLOCK <= (long long)batch) {
        // Full block: perfectly coalesced loads (lane i -> consecutive
        // 16B), then swizzled LDS redistribution to row owners.
        const long long f4Base = rowBase * 2;
        f32x4 a0 = xv[f4Base + t];
        f32x4 a1 = xv[f4Base + BLOCK + t];
        tile[swz(t)] = a0;
        tile[swz(BLOCK + t)] = a1;
        __syncthreads();
        f32x4 xa = tile[swz(2 * t)];
        f32x4 xb = tile[swz(2 * t + 1)];
        xin[0] = xa.x; xin[1] = xa.y; xin[2] = xa.z; xin[3] = xa.w;
        xin[4] = xb.x; xin[5] = xb.y; xin[6] = xb.z; xin[7] = xb.w;
    } else {
        // Tail block (not taken for batch = 2^21): original guarded path.
        // Branch condition is block-uniform, so the barrier above is safe.
        if (i >= batch) return;
        f32x4 xa = xv[2 * i];
        f32x4 xb = xv[2 * i + 1];
        xin[0] = xa.x; xin[1] = xa.y; xin[2] = xa.z; xin[3] = xa.w;
        xin[4] = xb.x; xin[5] = xb.y; xin[6] = xb.z; xin[7] = xb.w;
    }

    float h[HID];
    // input layer: linear only (no relu)
    #pragma unroll
    for (int j = 0; j < HID; ++j) {
        float s = b0[j];
        #pragma unroll
        for (int k = 0; k < IN_DIM; ++k) s = fmaf(xin[k], W0[j * IN_DIM + k], s);
        h[j] = s;
    }

    // hidden layers 1..4: linear + relu
    const float* __restrict__ Ws[4] = {W1, W2, W3, W4};
    const float* __restrict__ bs[4] = {b1, b2, b3, b4};
    #pragma unroll
    for (int l = 0; l < 4; ++l) {
        float g[HID];
        #pragma unroll
        for (int j = 0; j < HID; ++j) {
            float s = bs[l][j];
            #pragma unroll
            for (int k = 0; k < HID; ++k) s = fmaf(h[k], Ws[l][j * HID + k], s);
            g[j] = fmaxf(s, 0.0f);
        }
        #pragma unroll
        for (int j = 0; j < HID; ++j) h[j] = g[j];
    }

    // output layer: linear + relu
    float ov[OUT_DIM];
    #pragma unroll
    for (int j = 0; j < OUT_DIM; ++j) {
        float s = b5[j];
        #pragma unroll
        for (int k = 0; k < HID; ++k) s = fmaf(h[k], W5[j * HID + k], s);
        ov[j] = fmaxf(s, 0.0f);
    }

    // Coalesced non-temporal float4 store (output is never re-read).
    f32x4 o;
    o.x = ov[0]; o.y = ov[1]; o.z = ov[2]; o.w = ov[3];
    __builtin_nontemporal_store(o, reinterpret_cast<f32x4*>(out) + i);
}

extern "C" void kernel_launch(void* const* d_in, const int* in_sizes, int n_in,
                              void* d_out, int out_size, void* d_ws, size_t ws_size,
                              hipStream_t stream) {
    const float* x  = (const float*)d_in[0];
    const float* W0 = (const float*)d_in[1];
    const float* b0 = (const float*)d_in[2];
    const float* W1 = (const float*)d_in[3];
    const float* b1 = (const float*)d_in[4];
    const float* W2 = (const float*)d_in[5];
    const float* b2 = (const float*)d_in[6];
    const float* W3 = (const float*)d_in[7];
    const float* b3 = (const float*)d_in[8];
    const float* W4 = (const float*)d_in[9];
    const float* b4 = (const float*)d_in[10];
    const float* W5 = (const float*)d_in[11];
    const float* b5 = (const float*)d_in[12];
    float* out = (float*)d_out;

    int batch = in_sizes[0] / IN_DIM;
    int block = BLOCK;
    int grid = (batch + block - 1) / block;
    dqn_mlp_kernel<<<grid, block, 0, stream>>>(
        x, W0, b0, W1, b1, W2, b2, W3, b3, W4, b4, W5, b5, out, batch);
}